// Round 5
// baseline (3610.843 us; speedup 1.0000x reference)
//
#include <hip/hip_runtime.h>

#define Cn 16
#define Dn 96
#define Sn (Dn*Dn*Dn)        /* 884736 */
#define DSTRIDE (Dn*Dn)      /* 9216 */
#define ENC_NEG_INF 0x007FFFFFu

#define TW 24
#define TH 8
#define WH (TW+2)            /* 26 */
#define HH (TH+2)            /* 10 */
#define SLAB (WH*HH)         /* 260 positions */
#define ZCH 6                /* z-slices per block */
#define NTHR (TW*TH)         /* 192 threads = 3 waves */

typedef float v2f __attribute__((ext_vector_type(2)));

__device__ __forceinline__ v2f ld2(const float* p){
    v2f r; __builtin_memcpy(&r, p, 8); return r;
}
// monotonic float<->uint map for atomicMax on signed floats
__device__ __forceinline__ unsigned encf(float f){
    unsigned u = __float_as_uint(f);
    return (u & 0x80000000u) ? ~u : (u | 0x80000000u);
}
__device__ __forceinline__ float decf(unsigned u){
    return (u & 0x80000000u) ? __uint_as_float(u ^ 0x80000000u) : __uint_as_float(~u);
}
// tanh(x) = 1 - 2/(exp(2x)+1)
__device__ __forceinline__ float ftanh(float x){
    float t = __expf(2.0f*x);
    return 1.0f - __fdividef(2.0f, t + 1.0f);
}

__global__ void init_kernel(unsigned* __restrict__ maxv){
    if (threadIdx.x < 16) maxv[threadIdx.x] = ENC_NEG_INF;
}

// Reorder weights once:
//  w2T[k*64+j]=w2[j*64+k]; w3T[j*16+c]=w3[c*64+j];
//  w1P[k*48+q*16+c]=w1[k*48+3c+q]; wpT[t*48+q*16+c]=wp[(3c+q)*27+t]; bpP[q*16+c]=bp[3c+q]
__global__ void tr_kernel(const float* __restrict__ w2, const float* __restrict__ w3,
                          const float* __restrict__ w1, const float* __restrict__ wp,
                          const float* __restrict__ bp,
                          float* __restrict__ w2T, float* __restrict__ w3T,
                          float* __restrict__ w1P, float* __restrict__ wpT,
                          float* __restrict__ bpP){
    const int i = blockIdx.x*256 + threadIdx.x;
    if (i < 4096){ w2T[i] = w2[(i&63)*64 + (i>>6)]; }
    if (i < 1024){ w3T[i] = w3[(i&15)*64 + (i>>4)]; }
    if (i < 3072){ const int k=i/48, r=i%48, q=r>>4, c=r&15; w1P[i] = w1[k*48 + 3*c + q]; }
    if (i < 1296){ const int t=i/48, r=i%48, q=r>>4, c=r&15; wpT[i] = wp[(3*c+q)*27 + t]; }
    if (i < 48)  { const int q=i>>4, c=i&15; bpP[i] = bp[3*c + q]; }
}

// global max of x0 ch3 -> slot (pre-max for step 0; initial mask is all-ones)
__global__ __launch_bounds__(256) void prep_kernel(const float* __restrict__ x3,
    float* __restrict__ maskA, unsigned* __restrict__ slot)
{
    const int idx = blockIdx.x*256 + threadIdx.x;
    maskA[idx] = 1.0f;
    float v = x3[idx];
    #pragma unroll
    for (int o=32;o;o>>=1) v = fmaxf(v, __shfl_down(v, o));
    __shared__ float red[4];
    const int lane = threadIdx.x & 63, wid = threadIdx.x >> 6;
    if (lane==0) red[wid]=v;
    __syncthreads();
    if (threadIdx.x==0){
        float m = fmaxf(fmaxf(red[0],red[1]), fmaxf(red[2],red[3]));
        atomicMax(slot, encf(m));
    }
}

// z-marching fused update: ring of 3 LDS slabs holding PRE-MASKED x*m
// (zero-filled halo), conv reads from LDS, MLP 48->64->64->16 packed fp32.
// LDS layout [slot][cpair][pos]: lane stride 2 dwords -> conflict-free b64.
__global__ __launch_bounds__(NTHR, 3) void update_kernel(
    const float* __restrict__ xin, const float* __restrict__ min_,
    float* __restrict__ xout,
    const float* __restrict__ wpT, const float* __restrict__ bpP,
    const float* __restrict__ w1P, const float* __restrict__ b1,
    const float* __restrict__ w2T, const float* __restrict__ b2,
    const float* __restrict__ w3T, const float* __restrict__ b3,
    unsigned* __restrict__ slot_post)
{
    __shared__ v2f smem[3][8][SLAB];   // 3*8*260*8 = 49.92 KB
    const int tid = threadIdx.x;
    const int w0 = blockIdx.x*TW, h0 = blockIdx.y*TH, z0 = blockIdx.z*ZCH;
    const int lw = tid % TW, lh = tid / TW;

    auto load_slab = [&](int slot, int z){
        const bool zok = (unsigned)z < (unsigned)Dn;
        #pragma unroll 1
        for (int p = tid; p < SLAB; p += NTHR){
            const int ww = w0 + p % WH - 1;
            const int hh = h0 + p / WH - 1;
            const bool ok = zok && (unsigned)ww < (unsigned)Dn && (unsigned)hh < (unsigned)Dn;
            if (ok){
                const int base = z*DSTRIDE + hh*Dn + ww;
                const float m = min_[base];
                #pragma unroll
                for (int i=0;i<8;++i){
                    v2f v = { xin[(size_t)(2*i)*Sn + base] * m,
                              xin[(size_t)(2*i+1)*Sn + base] * m };
                    smem[slot][i][p] = v;
                }
            } else {
                const v2f zz = {0.0f, 0.0f};
                #pragma unroll
                for (int i=0;i<8;++i) smem[slot][i][p] = zz;
            }
        }
    };

    load_slab(0, z0-1);
    load_slab(1, z0);

    #pragma unroll 1
    for (int dz=0; dz<ZCH; ++dz){
        const int z = z0 + dz;
        load_slab((dz+2)%3, z+1);
        __syncthreads();

        // ---- dwconv 3x3x3 from LDS (pre-masked, zero-padded) ----
        v2f pv[24];
        #pragma unroll
        for (int j=0;j<24;++j) pv[j] = ld2(bpP + 2*j);

        #pragma unroll 1
        for (int zz=0; zz<3; ++zz){
            const v2f (* __restrict__ sl)[SLAB] = smem[(dz+zz)%3];
            const float* wz = wpT + zz*9*48;
            #pragma unroll
            for (int u=0; u<9; ++u){
                const int pos = (lh + u/3)*WH + (lw + u%3);
                const float* wrow = wz + u*48;
                #pragma unroll
                for (int i=0;i<8;++i){
                    const v2f xm = sl[i][pos];
                    pv[i]    = __builtin_elementwise_fma(ld2(wrow + 2*i),      xm, pv[i]);
                    pv[8+i]  = __builtin_elementwise_fma(ld2(wrow + 16 + 2*i), xm, pv[8+i]);
                    pv[16+i] = __builtin_elementwise_fma(ld2(wrow + 32 + 2*i), xm, pv[16+i]);
                }
            }
        }

        // ---- k-outer fused pw1+pw2 (packed) ----
        v2f acc2v[32];
        #pragma unroll
        for (int j=0;j<32;++j) acc2v[j] = ld2(b2 + 2*j);

        #pragma unroll 1
        for (int k=0;k<64;++k){
            const float* w1row = w1P + k*48;
            v2f av0 = {b1[k], 0.0f};
            v2f av1 = {0.0f, 0.0f};
            #pragma unroll
            for (int i=0;i<12;++i){
                av0 = __builtin_elementwise_fma(ld2(w1row + 4*i),     pv[2*i],   av0);
                av1 = __builtin_elementwise_fma(ld2(w1row + 4*i + 2), pv[2*i+1], av1);
            }
            const float a = (av0.x + av1.x) + (av0.y + av1.y);
            const float h1k = ftanh(a);
            const v2f hv = {h1k, h1k};
            const float* w2row = w2T + k*64;
            #pragma unroll
            for (int j=0;j<32;++j)
                acc2v[j] = __builtin_elementwise_fma(ld2(w2row + 2*j), hv, acc2v[j]);
        }

        // ---- pw3 (packed, fully unrolled) ----
        v2f oaccv[8];
        #pragma unroll
        for (int c=0;c<8;++c) oaccv[c] = ld2(b3 + 2*c);

        #pragma unroll
        for (int jp=0;jp<32;++jp){
            const float h2a = ftanh(acc2v[jp].x);
            const float h2b = ftanh(acc2v[jp].y);
            const v2f ha = {h2a, h2a}, hb = {h2b, h2b};
            const float* r0 = w3T + (2*jp)*16;
            const float* r1 = w3T + (2*jp+1)*16;
            #pragma unroll
            for (int c=0;c<8;++c){
                oaccv[c] = __builtin_elementwise_fma(ld2(r0 + 2*c), ha, oaccv[c]);
                oaccv[c] = __builtin_elementwise_fma(ld2(r1 + 2*c), hb, oaccv[c]);
            }
        }

        // ---- residual (center xm comes from LDS) + store + ch3 max ----
        const int idx = z*DSTRIDE + (h0+lh)*Dn + (w0+lw);
        const int cpos = (lh+1)*WH + (lw+1);
        const v2f (* __restrict__ sc)[SLAB] = smem[(dz+1)%3];
        float v3 = 0.0f;
        #pragma unroll
        for (int i=0;i<8;++i){
            const v2f cen = sc[i][cpos];
            const float xn0 = cen.x + oaccv[i].x;
            const float xn1 = cen.y + oaccv[i].y;
            xout[(size_t)(2*i)*Sn   + idx] = xn0;
            xout[(size_t)(2*i+1)*Sn + idx] = xn1;
            if (i==1) v3 = xn1;   // channel 3
        }

        #pragma unroll
        for (int o=32;o;o>>=1) v3 = fmaxf(v3, __shfl_down(v3, o));
        if ((tid & 63) == 0) atomicMax(slot_post, encf(v3));

        __syncthreads();
    }
}

// alive0 from masked old ch3, alive1 from unmasked new ch3; life mask includes
// the boundary zero x[:, :, -1, 48:, :]=0; also produces next step's pre-max
__global__ __launch_bounds__(256) void mask_kernel(
    const float* __restrict__ xin3, const float* __restrict__ min_,
    const float* __restrict__ xout3, float* __restrict__ mout,
    const unsigned* __restrict__ slot_pre, const unsigned* __restrict__ slot_post,
    unsigned* __restrict__ slot_next)
{
    const int idx = blockIdx.x*256 + threadIdx.x;
    const int w = idx % Dn;
    const int h = (idx / Dn) % Dn;
    const int d = idx / DSTRIDE;
    const float th0 = 0.1f * decf(*slot_pre);
    const float th1 = 0.1f * decf(*slot_post);
    float a0 = -INFINITY, a1 = -INFINITY;
    #pragma unroll
    for (int t=0;t<27;++t){
        const int dz=t/9-1, dy=(t/3)%3-1, dx=t%3-1;
        const int zz=d+dz, yy=h+dy, xx=w+dx;
        if ((unsigned)zz<(unsigned)Dn && (unsigned)yy<(unsigned)Dn &&
            (unsigned)xx<(unsigned)Dn){
            const int noff = idx + dz*DSTRIDE + dy*Dn + dx;
            a0 = fmaxf(a0, xin3[noff]*min_[noff]);
            a1 = fmaxf(a1, xout3[noff]);
        }
    }
    const bool life = (a0 > th0) && (a1 > th1) && !(d==Dn-1 && h>=48);
    const float mv = life ? 1.0f : 0.0f;
    mout[idx] = mv;

    float f3 = xout3[idx]*mv;   // final ch3 value -> pre-max of next step
    #pragma unroll
    for (int o=32;o;o>>=1) f3 = fmaxf(f3, __shfl_down(f3, o));
    __shared__ float red[4];
    const int lane = threadIdx.x & 63, wid = threadIdx.x >> 6;
    if (lane==0) red[wid]=f3;
    __syncthreads();
    if (threadIdx.x==0){
        float m = fmaxf(fmaxf(red[0],red[1]), fmaxf(red[2],red[3]));
        atomicMax(slot_next, encf(m));
    }
}

// final: apply last step's mask in place on d_out
__global__ __launch_bounds__(256) void apply_kernel(float* __restrict__ x,
    const float* __restrict__ mk)
{
    const int idx = blockIdx.x*256 + threadIdx.x;
    const float m = mk[idx];
    #pragma unroll
    for (int c=0;c<Cn;++c) x[(size_t)c*Sn+idx] *= m;
}

extern "C" void kernel_launch(void* const* d_in, const int* in_sizes, int n_in,
                              void* d_out, int out_size, void* d_ws, size_t ws_size,
                              hipStream_t stream)
{
    const float* x0 = (const float*)d_in[0];
    const float* wp = (const float*)d_in[1];
    const float* bp = (const float*)d_in[2];
    const float* w1 = (const float*)d_in[3];
    const float* b1 = (const float*)d_in[4];
    const float* w2 = (const float*)d_in[5];
    const float* b2 = (const float*)d_in[6];
    const float* w3 = (const float*)d_in[7];
    const float* b3 = (const float*)d_in[8];
    float* out = (float*)d_out;

    // ws: xbuf 16*Sn | maskA Sn | maskB Sn | maxv 16 u32 | w2T 4096 | w3T 1024 |
    //     w1P 3072 | wpT 1296 | bpP 48   (~63.75 MB)
    float* xbuf  = (float*)d_ws;
    float* maskA = xbuf + (size_t)Cn*Sn;
    float* maskB = maskA + Sn;
    unsigned* maxv = (unsigned*)(maskB + Sn);
    float* w2T = (float*)(maxv + 16);
    float* w3T = w2T + 4096;
    float* w1P = w3T + 1024;
    float* wpT = w1P + 3072;
    float* bpP = wpT + 1296;

    init_kernel<<<1, 64, 0, stream>>>(maxv);
    tr_kernel<<<16, 256, 0, stream>>>(w2, w3, w1, wp, bp, w2T, w3T, w1P, wpT, bpP);
    prep_kernel<<<Sn/256, 256, 0, stream>>>(x0 + (size_t)3*Sn, maskA, &maxv[0]);

    // ping-pong unmasked x_new between ws buffer and d_out; masks alternate A/B
    const float* xi[4] = {x0,   xbuf, out,  xbuf};
    float*       xo[4] = {xbuf, out,  xbuf, out};
    const float* mi[4] = {maskA, maskB, maskA, maskB};
    float*       mo[4] = {maskB, maskA, maskB, maskA};

    dim3 ugrid(Dn/TW, Dn/TH, Dn/ZCH);   // 4 x 12 x 16 = 768 blocks
    for (int s=0; s<4; ++s){
        update_kernel<<<ugrid, NTHR, 0, stream>>>(xi[s], mi[s], xo[s],
            wpT, bpP, w1P, b1, w2T, b2, w3T, b3, &maxv[2*s+1]);
        mask_kernel<<<Sn/256, 256, 0, stream>>>(xi[s]+(size_t)3*Sn, mi[s],
            xo[s]+(size_t)3*Sn, mo[s], &maxv[2*s], &maxv[2*s+1], &maxv[2*s+2]);
    }
    apply_kernel<<<Sn/256, 256, 0, stream>>>(out, maskA);
}